// Round 1
// baseline (1537.581 us; speedup 1.0000x reference)
//
#include <hip/hip_runtime.h>

#define D 128  // feature dim (D_IN == D_OUT == 128)

// ---------------------------------------------------------------------------
// Kernel 1: out-degree histogram (int atomics)
// ---------------------------------------------------------------------------
__global__ void deg_kernel(const int* __restrict__ src, int* __restrict__ deg, int E) {
    int i = blockIdx.x * blockDim.x + threadIdx.x;
    int stride = gridDim.x * blockDim.x;
    for (; i < E; i += stride) {
        atomicAdd(&deg[src[i]], 1);
    }
}

// ---------------------------------------------------------------------------
// Kernel 2: edge scatter-sum. One wave per edge; lane l handles floats
// [2l, 2l+1] of the 128-wide row. agg accumulator lives in d_out (pre-zeroed).
// ---------------------------------------------------------------------------
__global__ void scatter_kernel(const float* __restrict__ h,
                               const int* __restrict__ src,
                               const int* __restrict__ dst,
                               float* __restrict__ agg, int E) {
    int wave   = (int)((blockIdx.x * blockDim.x + threadIdx.x) >> 6);
    int lane   = threadIdx.x & 63;
    int nwaves = (int)((gridDim.x * blockDim.x) >> 6);
    for (int e = wave; e < E; e += nwaves) {
        int s = src[e];   // wave-uniform
        int d = dst[e];   // wave-uniform
        const float2 v = reinterpret_cast<const float2*>(h + (size_t)s * D)[lane];
        float* arow = agg + (size_t)d * D + lane * 2;
        atomicAdd(arow + 0, v.x);
        atomicAdd(arow + 1, v.y);
    }
}

// ---------------------------------------------------------------------------
// Kernel 3: in-place finishing GEMM:  out_rows = (agg_rows @ W) / deg + b
// Block = 256 threads, owns 64 rows. Stage agg tile -> LDS, compute, write
// back to the SAME rows (block-private => no inter-block race).
// Thread layout: wave w (t>>6) owns rows w*16..w*16+15; col pair j0 = (t&63)*2.
// ---------------------------------------------------------------------------
__global__ __launch_bounds__(256) void gemm_finish(float* __restrict__ out,
                                                   const float* __restrict__ Wm,
                                                   const float* __restrict__ bias,
                                                   const int* __restrict__ deg,
                                                   int N) {
    __shared__ __align__(16) float tile[64][D];
    const int r0 = blockIdx.x * 64;
    const int t  = threadIdx.x;

    // stage 64x128 f32 tile (2048 float4s, 8 per thread), zero-fill OOB rows
    #pragma unroll
    for (int i = 0; i < 8; ++i) {
        int flat4 = i * 256 + t;      // float4 index within tile
        int r     = flat4 >> 5;       // 32 float4 per row
        int c4    = flat4 & 31;
        int gr    = r0 + r;
        float4 v  = make_float4(0.f, 0.f, 0.f, 0.f);
        if (gr < N) v = reinterpret_cast<const float4*>(out + (size_t)gr * D)[c4];
        reinterpret_cast<float4*>(&tile[r][c4 * 4])[0] = v;
    }
    __syncthreads();

    const int wsel = t >> 6;          // which 16-row group
    const int j0   = (t & 63) * 2;    // this thread's column pair

    float acc[16][2];
    #pragma unroll
    for (int r = 0; r < 16; ++r) { acc[r][0] = 0.f; acc[r][1] = 0.f; }

    for (int k = 0; k < D; k += 4) {
        float2 w[4];
        #pragma unroll
        for (int kk = 0; kk < 4; ++kk)
            w[kk] = reinterpret_cast<const float2*>(Wm + (size_t)(k + kk) * D + j0)[0];
        #pragma unroll
        for (int r = 0; r < 16; ++r) {
            // broadcast LDS read: whole wave reads the same address
            float4 a = reinterpret_cast<const float4*>(&tile[wsel * 16 + r][k])[0];
            acc[r][0] += a.x * w[0].x + a.y * w[1].x + a.z * w[2].x + a.w * w[3].x;
            acc[r][1] += a.x * w[0].y + a.y * w[1].y + a.z * w[2].y + a.w * w[3].y;
        }
    }

    const float2 bb = reinterpret_cast<const float2*>(bias + j0)[0];
    #pragma unroll
    for (int r = 0; r < 16; ++r) {
        int gr = r0 + wsel * 16 + r;
        if (gr < N) {
            float sc = 1.0f / (float)deg[gr];   // norm^2 = deg^-1
            float2 o;
            o.x = acc[r][0] * sc + bb.x;
            o.y = acc[r][1] * sc + bb.y;
            reinterpret_cast<float2*>(out + (size_t)gr * D + j0)[0] = o;
        }
    }
}

// ---------------------------------------------------------------------------
extern "C" void kernel_launch(void* const* d_in, const int* in_sizes, int n_in,
                              void* d_out, int out_size, void* d_ws, size_t ws_size,
                              hipStream_t stream) {
    const float* h   = (const float*)d_in[0];
    const float* Wm  = (const float*)d_in[1];
    const float* bia = (const float*)d_in[2];
    const int*   src = (const int*)d_in[3];
    const int*   dst = (const int*)d_in[4];
    float*       out = (float*)d_out;

    const int N = in_sizes[0] / D;   // 100000
    const int E = in_sizes[3];       // 1700000

    int* deg = (int*)d_ws;

    // zero accumulator (d_out) and degree histogram each call
    hipMemsetAsync(out, 0, (size_t)out_size * sizeof(float), stream);
    hipMemsetAsync(deg, 0, (size_t)N * sizeof(int), stream);

    deg_kernel<<<2048, 256, 0, stream>>>(src, deg, E);

    scatter_kernel<<<8192, 256, 0, stream>>>(h, src, dst, out, E);

    int gblocks = (N + 63) / 64;
    gemm_finish<<<gblocks, 256, 0, stream>>>(out, Wm, bia, deg, N);
}

// Round 2
// 478.845 us; speedup vs baseline: 3.2110x; 3.2110x over previous
//
#include <hip/hip_runtime.h>

#define D 128  // feature dim (D_IN == D_OUT == 128)

// ---------------------------------------------------------------------------
// Histogram both degrees in one pass: indeg over dst, outdeg over src.
// ---------------------------------------------------------------------------
__global__ void degrees_kernel(const int* __restrict__ src, const int* __restrict__ dst,
                               int* __restrict__ outdeg, int* __restrict__ indeg, int E) {
    int i = blockIdx.x * blockDim.x + threadIdx.x;
    int stride = gridDim.x * blockDim.x;
    for (; i < E; i += stride) {
        atomicAdd(&outdeg[src[i]], 1);
        atomicAdd(&indeg[dst[i]], 1);
    }
}

// ---------------------------------------------------------------------------
// Exclusive scan of indeg[N] -> off[N+1], two-level (chunks of 1024).
// ---------------------------------------------------------------------------
#define SCAN_CHUNK 1024

__global__ __launch_bounds__(256) void scan_block_sums(const int* __restrict__ indeg,
                                                       int* __restrict__ bsum, int N) {
    __shared__ int red[256];
    const int base = blockIdx.x * SCAN_CHUNK;
    const int t = threadIdx.x;
    int s = 0;
    #pragma unroll
    for (int i = 0; i < 4; ++i) {
        int idx = base + t * 4 + i;
        if (idx < N) s += indeg[idx];
    }
    red[t] = s;
    __syncthreads();
    for (int o = 128; o > 0; o >>= 1) {
        if (t < o) red[t] += red[t + o];
        __syncthreads();
    }
    if (t == 0) bsum[blockIdx.x] = red[0];
}

__global__ void scan_bsum_serial(int* bsum, int nb) {
    if (threadIdx.x == 0 && blockIdx.x == 0) {
        int acc = 0;
        for (int i = 0; i < nb; ++i) { int v = bsum[i]; bsum[i] = acc; acc += v; }
    }
}

__global__ __launch_bounds__(256) void scan_write(const int* __restrict__ indeg,
                                                  const int* __restrict__ bsum,
                                                  int* __restrict__ off, int N, int E) {
    __shared__ int lds[256];
    const int base = blockIdx.x * SCAN_CHUNK;
    const int t = threadIdx.x;
    int v[4]; int s = 0;
    #pragma unroll
    for (int i = 0; i < 4; ++i) {
        int idx = base + t * 4 + i;
        v[i] = (idx < N) ? indeg[idx] : 0;
        s += v[i];
    }
    lds[t] = s;
    __syncthreads();
    // Hillis-Steele inclusive scan over 256 thread-sums
    for (int d = 1; d < 256; d <<= 1) {
        int x = (t >= d) ? lds[t - d] : 0;
        __syncthreads();
        lds[t] += x;
        __syncthreads();
    }
    int excl = lds[t] - s + bsum[blockIdx.x];
    #pragma unroll
    for (int i = 0; i < 4; ++i) {
        int idx = base + t * 4 + i;
        if (idx < N) off[idx] = excl;
        excl += v[i];
    }
    if (blockIdx.x == 0 && t == 0) off[N] = E;
}

// ---------------------------------------------------------------------------
// CSR fill: place src id of each edge into its dst bucket (int atomics only).
// ---------------------------------------------------------------------------
__global__ void csr_fill(const int* __restrict__ src, const int* __restrict__ dst,
                         int* __restrict__ cursor, int* __restrict__ csr_src, int E) {
    int i = blockIdx.x * blockDim.x + threadIdx.x;
    int stride = gridDim.x * blockDim.x;
    for (; i < E; i += stride) {
        int slot = atomicAdd(&cursor[dst[i]], 1);
        csr_src[slot] = src[i];
    }
}

// ---------------------------------------------------------------------------
// Pull aggregation: one wave per node; lane l owns cols {2l, 2l+1}.
// Pure loads + one store per row; no float atomics.
// ---------------------------------------------------------------------------
__global__ __launch_bounds__(256) void aggregate_kernel(const float* __restrict__ h,
                                                        const int* __restrict__ off,
                                                        const int* __restrict__ csr_src,
                                                        float* __restrict__ agg, int N) {
    const int wid  = (int)((blockIdx.x * blockDim.x + threadIdx.x) >> 6);
    const int lane = threadIdx.x & 63;
    const int nw   = (int)((gridDim.x * blockDim.x) >> 6);
    for (int n = wid; n < N; n += nw) {
        const int e0 = off[n], e1 = off[n + 1];
        float2 acc = make_float2(0.f, 0.f);
        int e = e0;
        for (; e + 1 < e1; e += 2) {
            int s0 = csr_src[e], s1 = csr_src[e + 1];
            float2 a = reinterpret_cast<const float2*>(h + (size_t)s0 * D)[lane];
            float2 b = reinterpret_cast<const float2*>(h + (size_t)s1 * D)[lane];
            acc.x += a.x + b.x;
            acc.y += a.y + b.y;
        }
        if (e < e1) {
            int s0 = csr_src[e];
            float2 a = reinterpret_cast<const float2*>(h + (size_t)s0 * D)[lane];
            acc.x += a.x;
            acc.y += a.y;
        }
        reinterpret_cast<float2*>(agg + (size_t)n * D)[lane] = acc;
    }
}

// ---------------------------------------------------------------------------
// Fallback (round-1) kernels: atomic scatter path, used only if ws too small.
// ---------------------------------------------------------------------------
__global__ void scatter_kernel(const float* __restrict__ h,
                               const int* __restrict__ src,
                               const int* __restrict__ dst,
                               float* __restrict__ agg, int E) {
    int wave   = (int)((blockIdx.x * blockDim.x + threadIdx.x) >> 6);
    int lane   = threadIdx.x & 63;
    int nwaves = (int)((gridDim.x * blockDim.x) >> 6);
    for (int e = wave; e < E; e += nwaves) {
        int s = src[e];
        int d = dst[e];
        const float2 v = reinterpret_cast<const float2*>(h + (size_t)s * D)[lane];
        float* arow = agg + (size_t)d * D + lane * 2;
        atomicAdd(arow + 0, v.x);
        atomicAdd(arow + 1, v.y);
    }
}

__global__ void deg_kernel(const int* __restrict__ src, int* __restrict__ deg, int E) {
    int i = blockIdx.x * blockDim.x + threadIdx.x;
    int stride = gridDim.x * blockDim.x;
    for (; i < E; i += stride) atomicAdd(&deg[src[i]], 1);
}

// ---------------------------------------------------------------------------
// In-place finishing GEMM:  out_rows = (agg_rows @ W) / outdeg + b
// ---------------------------------------------------------------------------
__global__ __launch_bounds__(256) void gemm_finish(float* __restrict__ out,
                                                   const float* __restrict__ Wm,
                                                   const float* __restrict__ bias,
                                                   const int* __restrict__ deg,
                                                   int N) {
    __shared__ __align__(16) float tile[64][D];
    const int r0 = blockIdx.x * 64;
    const int t  = threadIdx.x;

    #pragma unroll
    for (int i = 0; i < 8; ++i) {
        int flat4 = i * 256 + t;
        int r     = flat4 >> 5;
        int c4    = flat4 & 31;
        int gr    = r0 + r;
        float4 v  = make_float4(0.f, 0.f, 0.f, 0.f);
        if (gr < N) v = reinterpret_cast<const float4*>(out + (size_t)gr * D)[c4];
        reinterpret_cast<float4*>(&tile[r][c4 * 4])[0] = v;
    }
    __syncthreads();

    const int wsel = t >> 6;
    const int j0   = (t & 63) * 2;

    float acc[16][2];
    #pragma unroll
    for (int r = 0; r < 16; ++r) { acc[r][0] = 0.f; acc[r][1] = 0.f; }

    for (int k = 0; k < D; k += 4) {
        float2 w[4];
        #pragma unroll
        for (int kk = 0; kk < 4; ++kk)
            w[kk] = reinterpret_cast<const float2*>(Wm + (size_t)(k + kk) * D + j0)[0];
        #pragma unroll
        for (int r = 0; r < 16; ++r) {
            float4 a = reinterpret_cast<const float4*>(&tile[wsel * 16 + r][k])[0];
            acc[r][0] += a.x * w[0].x + a.y * w[1].x + a.z * w[2].x + a.w * w[3].x;
            acc[r][1] += a.x * w[0].y + a.y * w[1].y + a.z * w[2].y + a.w * w[3].y;
        }
    }

    const float2 bb = reinterpret_cast<const float2*>(bias + j0)[0];
    #pragma unroll
    for (int r = 0; r < 16; ++r) {
        int gr = r0 + wsel * 16 + r;
        if (gr < N) {
            float sc = 1.0f / (float)deg[gr];
            float2 o;
            o.x = acc[r][0] * sc + bb.x;
            o.y = acc[r][1] * sc + bb.y;
            reinterpret_cast<float2*>(out + (size_t)gr * D + j0)[0] = o;
        }
    }
}

// ---------------------------------------------------------------------------
extern "C" void kernel_launch(void* const* d_in, const int* in_sizes, int n_in,
                              void* d_out, int out_size, void* d_ws, size_t ws_size,
                              hipStream_t stream) {
    const float* h   = (const float*)d_in[0];
    const float* Wm  = (const float*)d_in[1];
    const float* bia = (const float*)d_in[2];
    const int*   src = (const int*)d_in[3];
    const int*   dst = (const int*)d_in[4];
    float*       out = (float*)d_out;

    const int N = in_sizes[0] / D;   // 100000
    const int E = in_sizes[3];       // 1700000

    const int nb = (N + SCAN_CHUNK - 1) / SCAN_CHUNK;

    // ws layout (ints): indeg[N] | off[N+1] | cursor[N] | outdeg[N] | bsum[nb pad 1056] | csr_src[E]
    size_t need_ints = (size_t)4 * N + 2 + 1056 + (size_t)E;
    if (ws_size >= need_ints * sizeof(int)) {
        int* indeg  = (int*)d_ws;
        int* off    = indeg + N;
        int* cursor = off + (N + 1);
        int* outdeg = cursor + N;
        int* bsum   = outdeg + N;
        int* csr    = bsum + 1056;

        hipMemsetAsync(indeg,  0, (size_t)N * sizeof(int), stream);
        hipMemsetAsync(outdeg, 0, (size_t)N * sizeof(int), stream);

        degrees_kernel<<<2048, 256, 0, stream>>>(src, dst, outdeg, indeg, E);

        scan_block_sums<<<nb, 256, 0, stream>>>(indeg, bsum, N);
        scan_bsum_serial<<<1, 64, 0, stream>>>(bsum, nb);
        scan_write<<<nb, 256, 0, stream>>>(indeg, bsum, off, N, E);

        hipMemcpyAsync(cursor, off, (size_t)N * sizeof(int),
                       hipMemcpyDeviceToDevice, stream);
        csr_fill<<<2048, 256, 0, stream>>>(src, dst, cursor, csr, E);

        // one wave per node (4 waves / block)
        int ablocks = (N + 3) / 4;
        aggregate_kernel<<<ablocks, 256, 0, stream>>>(h, off, csr, out, N);

        int gblocks = (N + 63) / 64;
        gemm_finish<<<gblocks, 256, 0, stream>>>(out, Wm, bia, outdeg, N);
    } else {
        // fallback: atomic scatter path (round-1)
        int* deg = (int*)d_ws;
        hipMemsetAsync(out, 0, (size_t)out_size * sizeof(float), stream);
        hipMemsetAsync(deg, 0, (size_t)N * sizeof(int), stream);
        deg_kernel<<<2048, 256, 0, stream>>>(src, deg, E);
        scatter_kernel<<<8192, 256, 0, stream>>>(h, src, dst, out, E);
        int gblocks = (N + 63) / 64;
        gemm_finish<<<gblocks, 256, 0, stream>>>(out, Wm, bia, deg, N);
    }
}

// Round 3
// 431.645 us; speedup vs baseline: 3.5621x; 1.1093x over previous
//
#include <hip/hip_runtime.h>

#define D 128           // feature dim
#define CHUNK 8192      // edges per partition block
#define NCHUNK_MAX 256  // supports E <= 2M
#define NB_MAX 512      // supports N <= 131072 (bucket = 256 nodes)
#define STAGE_CAP 12288 // C2 LDS stage entries

// ---------------------------------------------------------------------------
// out-degree histogram (int atomics) — needed for the norm
// ---------------------------------------------------------------------------
__global__ void deg_kernel(const int* __restrict__ src, int* __restrict__ deg, int E) {
    int i = blockIdx.x * blockDim.x + threadIdx.x;
    int stride = gridDim.x * blockDim.x;
    for (; i < E; i += stride) atomicAdd(&deg[src[i]], 1);
}

// ---------------------------------------------------------------------------
// C1: partition each 8192-edge chunk by bucket (dst>>8), dense output.
// pairs word = (dst&255)<<24 | src   (requires src < 2^24)
// ---------------------------------------------------------------------------
__global__ __launch_bounds__(256) void part_chunk(const int* __restrict__ src,
                                                  const int* __restrict__ dst,
                                                  unsigned int* __restrict__ pairs,
                                                  int* __restrict__ cnt_g,
                                                  int* __restrict__ loff_g,
                                                  int E, int nb) {
    __shared__ int hist[NB_MAX];
    __shared__ int lofs[NB_MAX];
    __shared__ int cur[NB_MAX];
    __shared__ unsigned int stage[CHUNK];

    const int t  = threadIdx.x;
    const int c  = blockIdx.x;
    const int e0 = c * CHUNK;
    const int n  = min(CHUNK, E - e0);

    for (int i = t; i < nb; i += 256) hist[i] = 0;
    __syncthreads();

    // pass 1: bucket histogram
    for (int i = t; i < n; i += 256) {
        int d = dst[e0 + i];
        atomicAdd(&hist[d >> 8], 1);
    }
    __syncthreads();

    // exclusive scan (serial by thread 0 — nb <= 512)
    if (t == 0) {
        int acc = 0;
        for (int i = 0; i < nb; ++i) { lofs[i] = acc; acc += hist[i]; }
    }
    __syncthreads();

    // export tables + init cursors
    for (int i = t; i < nb; i += 256) {
        cnt_g[c * nb + i]  = hist[i];
        loff_g[c * nb + i] = lofs[i];
        cur[i] = lofs[i];
    }
    __syncthreads();

    // pass 2: scatter into LDS stage
    for (int i = t; i < n; i += 256) {
        int d = dst[e0 + i];
        int s = src[e0 + i];
        int slot = atomicAdd(&cur[d >> 8], 1);
        stage[slot] = ((unsigned int)(d & 255) << 24) | (unsigned int)s;
    }
    __syncthreads();

    // pass 3: dense streamout
    for (int i = t; i < n; i += 256) pairs[e0 + i] = stage[i];
}

// ---------------------------------------------------------------------------
// C1b: bucket totals across chunks + exclusive scan -> bb[nb+1]
// ---------------------------------------------------------------------------
__global__ __launch_bounds__(256) void bucket_scan(const int* __restrict__ cnt_g,
                                                   int* __restrict__ bb,
                                                   int nb, int nchunk, int E) {
    __shared__ int tot[NB_MAX];
    const int t = threadIdx.x;
    for (int b = t; b < nb; b += 256) {
        int s = 0;
        for (int c = 0; c < nchunk; ++c) s += cnt_g[c * nb + b];
        tot[b] = s;
    }
    __syncthreads();
    if (t == 0) {
        int acc = 0;
        for (int b = 0; b < nb; ++b) { bb[b] = acc; acc += tot[b]; }
        bb[nb] = acc;   // == E
    }
}

// ---------------------------------------------------------------------------
// C2: per-bucket counting sort by local dst -> CSR segment + off[] entries.
// ---------------------------------------------------------------------------
__global__ __launch_bounds__(256) void csr_build(const unsigned int* __restrict__ pairs,
                                                 const int* __restrict__ cnt_g,
                                                 const int* __restrict__ loff_g,
                                                 const int* __restrict__ bb,
                                                 int* __restrict__ off,
                                                 int* __restrict__ csr,
                                                 int nb, int nchunk, int N, int E) {
    __shared__ int sec_base[NCHUNK_MAX + 1];
    __shared__ int sec_lo[NCHUNK_MAX];
    __shared__ int dhist[256];
    __shared__ int dcur[256];
    __shared__ unsigned int stage[STAGE_CAP];

    const int t = threadIdx.x;
    const int b = blockIdx.x;

    for (int c = t; c < nchunk; c += 256) {
        sec_base[c] = cnt_g[c * nb + b];
        sec_lo[c]   = loff_g[c * nb + b];
    }
    if (t < 256) dhist[t] = 0;
    __syncthreads();
    if (t == 0) {
        int acc = 0;
        for (int c = 0; c < nchunk; ++c) { int v = sec_base[c]; sec_base[c] = acc; acc += v; }
        sec_base[nchunk] = acc;
    }
    __syncthreads();

    const int total  = sec_base[nchunk];
    const int base_g = bb[b];

    // pass 1: local-dst histogram
    for (int j = t; j < total; j += 256) {
        int lo = 0, hi = nchunk - 1;
        while (lo < hi) { int mid = (lo + hi + 1) >> 1; if (sec_base[mid] <= j) lo = mid; else hi = mid - 1; }
        unsigned int p = pairs[lo * CHUNK + sec_lo[lo] + (j - sec_base[lo])];
        atomicAdd(&dhist[p >> 24], 1);
    }
    __syncthreads();

    if (t == 0) {
        int acc = 0;
        for (int i = 0; i < 256; ++i) { int v = dhist[i]; dhist[i] = acc; acc += v; }
    }
    __syncthreads();

    // CSR offsets for this bucket's nodes
    {
        int node = (b << 8) + t;
        if (node < N) off[node] = base_g + dhist[t];
        if (b == gridDim.x - 1 && t == 0) off[N] = E;
    }
    dcur[t] = dhist[t];
    __syncthreads();

    // pass 2: scatter src into LDS stage ordered by local dst
    for (int j = t; j < total; j += 256) {
        int lo = 0, hi = nchunk - 1;
        while (lo < hi) { int mid = (lo + hi + 1) >> 1; if (sec_base[mid] <= j) lo = mid; else hi = mid - 1; }
        unsigned int p = pairs[lo * CHUNK + sec_lo[lo] + (j - sec_base[lo])];
        int slot = atomicAdd(&dcur[p >> 24], 1);
        unsigned int s = p & 0xFFFFFFu;
        if (slot < STAGE_CAP) stage[slot] = s;
        else csr[base_g + slot] = (int)s;   // overflow safety (pathological skew only)
    }
    __syncthreads();

    // pass 3: dense streamout
    int lim = min(total, STAGE_CAP);
    for (int j = t; j < lim; j += 256) csr[base_g + j] = (int)stage[j];
}

// ---------------------------------------------------------------------------
// Pull aggregation: one wave per node; lane l owns cols {2l, 2l+1}. (unchanged)
// ---------------------------------------------------------------------------
__global__ __launch_bounds__(256) void aggregate_kernel(const float* __restrict__ h,
                                                        const int* __restrict__ off,
                                                        const int* __restrict__ csr_src,
                                                        float* __restrict__ agg, int N) {
    const int wid  = (int)((blockIdx.x * blockDim.x + threadIdx.x) >> 6);
    const int lane = threadIdx.x & 63;
    const int nw   = (int)((gridDim.x * blockDim.x) >> 6);
    for (int n = wid; n < N; n += nw) {
        const int e0 = off[n], e1 = off[n + 1];
        float2 acc = make_float2(0.f, 0.f);
        int e = e0;
        for (; e + 1 < e1; e += 2) {
            int s0 = csr_src[e], s1 = csr_src[e + 1];
            float2 a = reinterpret_cast<const float2*>(h + (size_t)s0 * D)[lane];
            float2 b = reinterpret_cast<const float2*>(h + (size_t)s1 * D)[lane];
            acc.x += a.x + b.x;
            acc.y += a.y + b.y;
        }
        if (e < e1) {
            int s0 = csr_src[e];
            float2 a = reinterpret_cast<const float2*>(h + (size_t)s0 * D)[lane];
            acc.x += a.x;
            acc.y += a.y;
        }
        reinterpret_cast<float2*>(agg + (size_t)n * D)[lane] = acc;
    }
}

// ---------------------------------------------------------------------------
// Fallback (round-1) scatter path kernels
// ---------------------------------------------------------------------------
__global__ void scatter_kernel(const float* __restrict__ h,
                               const int* __restrict__ src,
                               const int* __restrict__ dst,
                               float* __restrict__ agg, int E) {
    int wave   = (int)((blockIdx.x * blockDim.x + threadIdx.x) >> 6);
    int lane   = threadIdx.x & 63;
    int nwaves = (int)((gridDim.x * blockDim.x) >> 6);
    for (int e = wave; e < E; e += nwaves) {
        int s = src[e];
        int d = dst[e];
        const float2 v = reinterpret_cast<const float2*>(h + (size_t)s * D)[lane];
        float* arow = agg + (size_t)d * D + lane * 2;
        atomicAdd(arow + 0, v.x);
        atomicAdd(arow + 1, v.y);
    }
}

// ---------------------------------------------------------------------------
// In-place finishing GEMM:  out_rows = (agg_rows @ W) / outdeg + b (unchanged)
// ---------------------------------------------------------------------------
__global__ __launch_bounds__(256) void gemm_finish(float* __restrict__ out,
                                                   const float* __restrict__ Wm,
                                                   const float* __restrict__ bias,
                                                   const int* __restrict__ deg,
                                                   int N) {
    __shared__ __align__(16) float tile[64][D];
    const int r0 = blockIdx.x * 64;
    const int t  = threadIdx.x;

    #pragma unroll
    for (int i = 0; i < 8; ++i) {
        int flat4 = i * 256 + t;
        int r     = flat4 >> 5;
        int c4    = flat4 & 31;
        int gr    = r0 + r;
        float4 v  = make_float4(0.f, 0.f, 0.f, 0.f);
        if (gr < N) v = reinterpret_cast<const float4*>(out + (size_t)gr * D)[c4];
        reinterpret_cast<float4*>(&tile[r][c4 * 4])[0] = v;
    }
    __syncthreads();

    const int wsel = t >> 6;
    const int j0   = (t & 63) * 2;

    float acc[16][2];
    #pragma unroll
    for (int r = 0; r < 16; ++r) { acc[r][0] = 0.f; acc[r][1] = 0.f; }

    for (int k = 0; k < D; k += 4) {
        float2 w[4];
        #pragma unroll
        for (int kk = 0; kk < 4; ++kk)
            w[kk] = reinterpret_cast<const float2*>(Wm + (size_t)(k + kk) * D + j0)[0];
        #pragma unroll
        for (int r = 0; r < 16; ++r) {
            float4 a = reinterpret_cast<const float4*>(&tile[wsel * 16 + r][k])[0];
            acc[r][0] += a.x * w[0].x + a.y * w[1].x + a.z * w[2].x + a.w * w[3].x;
            acc[r][1] += a.x * w[0].y + a.y * w[1].y + a.z * w[2].y + a.w * w[3].y;
        }
    }

    const float2 bb = reinterpret_cast<const float2*>(bias + j0)[0];
    #pragma unroll
    for (int r = 0; r < 16; ++r) {
        int gr = r0 + wsel * 16 + r;
        if (gr < N) {
            float sc = 1.0f / (float)deg[gr];
            float2 o;
            o.x = acc[r][0] * sc + bb.x;
            o.y = acc[r][1] * sc + bb.y;
            reinterpret_cast<float2*>(out + (size_t)gr * D + j0)[0] = o;
        }
    }
}

// ---------------------------------------------------------------------------
extern "C" void kernel_launch(void* const* d_in, const int* in_sizes, int n_in,
                              void* d_out, int out_size, void* d_ws, size_t ws_size,
                              hipStream_t stream) {
    const float* h   = (const float*)d_in[0];
    const float* Wm  = (const float*)d_in[1];
    const float* bia = (const float*)d_in[2];
    const int*   src = (const int*)d_in[3];
    const int*   dst = (const int*)d_in[4];
    float*       out = (float*)d_out;

    const int N = in_sizes[0] / D;   // 100000
    const int E = in_sizes[3];       // 1700000

    const int nb     = (N + 255) >> 8;
    const int nchunk = (E + CHUNK - 1) / CHUNK;

    // ws (ints): outdeg[N] | off[N+1] | cnt[nchunk*nb] | loff[nchunk*nb] |
    //            bb[nb+1] | pairs[nchunk*CHUNK] | csr[E]
    size_t need_ints = (size_t)N + (N + 1) + (size_t)2 * nchunk * nb + (nb + 1)
                     + (size_t)nchunk * CHUNK + (size_t)E;

    if (ws_size >= need_ints * sizeof(int) && N < (1 << 24) &&
        nb <= NB_MAX && nchunk <= NCHUNK_MAX) {
        int* outdeg = (int*)d_ws;
        int* off    = outdeg + N;
        int* cnt_g  = off + (N + 1);
        int* loff_g = cnt_g + (size_t)nchunk * nb;
        int* bb     = loff_g + (size_t)nchunk * nb;
        unsigned int* pairs = (unsigned int*)(bb + (nb + 1));
        int* csr    = (int*)(pairs + (size_t)nchunk * CHUNK);

        hipMemsetAsync(outdeg, 0, (size_t)N * sizeof(int), stream);
        deg_kernel<<<2048, 256, 0, stream>>>(src, outdeg, E);

        part_chunk<<<nchunk, 256, 0, stream>>>(src, dst, pairs, cnt_g, loff_g, E, nb);
        bucket_scan<<<1, 256, 0, stream>>>(cnt_g, bb, nb, nchunk, E);
        csr_build<<<nb, 256, 0, stream>>>(pairs, cnt_g, loff_g, bb, off, csr,
                                          nb, nchunk, N, E);

        int ablocks = (N + 3) / 4;
        aggregate_kernel<<<ablocks, 256, 0, stream>>>(h, off, csr, out, N);

        int gblocks = (N + 63) / 64;
        gemm_finish<<<gblocks, 256, 0, stream>>>(out, Wm, bia, outdeg, N);
    } else {
        // fallback: atomic scatter path
        int* deg = (int*)d_ws;
        hipMemsetAsync(out, 0, (size_t)out_size * sizeof(float), stream);
        hipMemsetAsync(deg, 0, (size_t)N * sizeof(int), stream);
        deg_kernel<<<2048, 256, 0, stream>>>(src, deg, E);
        scatter_kernel<<<8192, 256, 0, stream>>>(h, src, dst, out, E);
        int gblocks = (N + 63) / 64;
        gemm_finish<<<gblocks, 256, 0, stream>>>(out, Wm, bia, deg, N);
    }
}

// Round 4
// 379.633 us; speedup vs baseline: 4.0502x; 1.1370x over previous
//
#include <hip/hip_runtime.h>

#define D 128           // feature dim
#define CHUNK 8192      // edges per partition block
#define NCHUNK_MAX 256  // supports E <= 2M
#define NB_MAX 512      // supports N <= 131072 (bucket = 256 nodes)
#define STAGE_CAP 12288 // C2 LDS stage entries

// ---------------------------------------------------------------------------
// bf16 helpers (manual RNE pack / unpack; element 2c in low 16 bits)
// ---------------------------------------------------------------------------
__device__ __forceinline__ unsigned int pack_bf16(float a, float b) {
    unsigned int ua = __float_as_uint(a), ub = __float_as_uint(b);
    ua = (ua + 0x7fffu + ((ua >> 16) & 1u)) >> 16;
    ub = (ub + 0x7fffu + ((ub >> 16) & 1u)) >> 16;
    return (ub << 16) | (ua & 0xffffu);
}

// ---------------------------------------------------------------------------
// out-degree histogram (standalone, fallback path only)
// ---------------------------------------------------------------------------
__global__ void deg_kernel(const int* __restrict__ src, int* __restrict__ deg, int E) {
    int i = blockIdx.x * blockDim.x + threadIdx.x;
    int stride = gridDim.x * blockDim.x;
    for (; i < E; i += stride) atomicAdd(&deg[src[i]], 1);
}

// ---------------------------------------------------------------------------
// C1: partition each 8192-edge chunk by bucket (dst>>8), dense output.
// pairs word = (dst&255)<<24 | src   (requires src < 2^24)
// Also accumulates the global out-degree histogram (folded-in deg_kernel).
// ---------------------------------------------------------------------------
__global__ __launch_bounds__(256) void part_chunk(const int* __restrict__ src,
                                                  const int* __restrict__ dst,
                                                  unsigned int* __restrict__ pairs,
                                                  int* __restrict__ cnt_g,
                                                  int* __restrict__ loff_g,
                                                  int* __restrict__ outdeg,
                                                  int E, int nb) {
    __shared__ int hist[NB_MAX];
    __shared__ int lofs[NB_MAX];
    __shared__ int cur[NB_MAX];
    __shared__ unsigned int stage[CHUNK];

    const int t  = threadIdx.x;
    const int c  = blockIdx.x;
    const int e0 = c * CHUNK;
    const int n  = min(CHUNK, E - e0);

    for (int i = t; i < nb; i += 256) hist[i] = 0;
    __syncthreads();

    // pass 1: bucket histogram
    for (int i = t; i < n; i += 256) {
        int d = dst[e0 + i];
        atomicAdd(&hist[d >> 8], 1);
    }
    __syncthreads();

    if (t == 0) {
        int acc = 0;
        for (int i = 0; i < nb; ++i) { lofs[i] = acc; acc += hist[i]; }
    }
    __syncthreads();

    for (int i = t; i < nb; i += 256) {
        cnt_g[c * nb + i]  = hist[i];
        loff_g[c * nb + i] = lofs[i];
        cur[i] = lofs[i];
    }
    __syncthreads();

    // pass 2: scatter into LDS stage + out-degree histogram
    for (int i = t; i < n; i += 256) {
        int d = dst[e0 + i];
        int s = src[e0 + i];
        atomicAdd(&outdeg[s], 1);
        int slot = atomicAdd(&cur[d >> 8], 1);
        stage[slot] = ((unsigned int)(d & 255) << 24) | (unsigned int)s;
    }
    __syncthreads();

    // pass 3: dense streamout
    for (int i = t; i < n; i += 256) pairs[e0 + i] = stage[i];
}

// ---------------------------------------------------------------------------
// C1b: bucket totals across chunks + exclusive scan -> bb[nb+1]
// ---------------------------------------------------------------------------
__global__ __launch_bounds__(256) void bucket_scan(const int* __restrict__ cnt_g,
                                                   int* __restrict__ bb,
                                                   int nb, int nchunk, int E) {
    __shared__ int tot[NB_MAX];
    const int t = threadIdx.x;
    for (int b = t; b < nb; b += 256) {
        int s = 0;
        for (int c = 0; c < nchunk; ++c) s += cnt_g[c * nb + b];
        tot[b] = s;
    }
    __syncthreads();
    if (t == 0) {
        int acc = 0;
        for (int b = 0; b < nb; ++b) { bb[b] = acc; acc += tot[b]; }
        bb[nb] = acc;
    }
}

// ---------------------------------------------------------------------------
// C2: per-bucket counting sort by local dst -> CSR segment + off[] entries.
// ---------------------------------------------------------------------------
__global__ __launch_bounds__(256) void csr_build(const unsigned int* __restrict__ pairs,
                                                 const int* __restrict__ cnt_g,
                                                 const int* __restrict__ loff_g,
                                                 const int* __restrict__ bb,
                                                 int* __restrict__ off,
                                                 int* __restrict__ csr,
                                                 int nb, int nchunk, int N, int E) {
    __shared__ int sec_base[NCHUNK_MAX + 1];
    __shared__ int sec_lo[NCHUNK_MAX];
    __shared__ int dhist[256];
    __shared__ int dcur[256];
    __shared__ unsigned int stage[STAGE_CAP];

    const int t = threadIdx.x;
    const int b = blockIdx.x;

    for (int c = t; c < nchunk; c += 256) {
        sec_base[c] = cnt_g[c * nb + b];
        sec_lo[c]   = loff_g[c * nb + b];
    }
    if (t < 256) dhist[t] = 0;
    __syncthreads();
    if (t == 0) {
        int acc = 0;
        for (int c = 0; c < nchunk; ++c) { int v = sec_base[c]; sec_base[c] = acc; acc += v; }
        sec_base[nchunk] = acc;
    }
    __syncthreads();

    const int total  = sec_base[nchunk];
    const int base_g = bb[b];

    for (int j = t; j < total; j += 256) {
        int lo = 0, hi = nchunk - 1;
        while (lo < hi) { int mid = (lo + hi + 1) >> 1; if (sec_base[mid] <= j) lo = mid; else hi = mid - 1; }
        unsigned int p = pairs[lo * CHUNK + sec_lo[lo] + (j - sec_base[lo])];
        atomicAdd(&dhist[p >> 24], 1);
    }
    __syncthreads();

    if (t == 0) {
        int acc = 0;
        for (int i = 0; i < 256; ++i) { int v = dhist[i]; dhist[i] = acc; acc += v; }
    }
    __syncthreads();

    {
        int node = (b << 8) + t;
        if (node < N) off[node] = base_g + dhist[t];
        if (b == gridDim.x - 1 && t == 0) off[N] = E;
    }
    dcur[t] = dhist[t];
    __syncthreads();

    for (int j = t; j < total; j += 256) {
        int lo = 0, hi = nchunk - 1;
        while (lo < hi) { int mid = (lo + hi + 1) >> 1; if (sec_base[mid] <= j) lo = mid; else hi = mid - 1; }
        unsigned int p = pairs[lo * CHUNK + sec_lo[lo] + (j - sec_base[lo])];
        int slot = atomicAdd(&dcur[p >> 24], 1);
        unsigned int s = p & 0xFFFFFFu;
        if (slot < STAGE_CAP) stage[slot] = s;
        else csr[base_g + slot] = (int)s;
    }
    __syncthreads();

    int lim = min(total, STAGE_CAP);
    for (int j = t; j < lim; j += 256) csr[base_g + j] = (int)stage[j];
}

// ---------------------------------------------------------------------------
// GEMM: hw(bf16) = h @ W.   64-row tile per block, identical structure to the
// old gemm_finish but reads h and writes packed bf16 (one uint per col-pair).
// ---------------------------------------------------------------------------
__global__ __launch_bounds__(256) void gemm_hw(const float* __restrict__ h,
                                               const float* __restrict__ Wm,
                                               unsigned int* __restrict__ hw,
                                               int N) {
    __shared__ __align__(16) float tile[64][D];
    const int r0 = blockIdx.x * 64;
    const int t  = threadIdx.x;

    #pragma unroll
    for (int i = 0; i < 8; ++i) {
        int flat4 = i * 256 + t;
        int r     = flat4 >> 5;
        int c4    = flat4 & 31;
        int gr    = r0 + r;
        float4 v  = make_float4(0.f, 0.f, 0.f, 0.f);
        if (gr < N) v = reinterpret_cast<const float4*>(h + (size_t)gr * D)[c4];
        reinterpret_cast<float4*>(&tile[r][c4 * 4])[0] = v;
    }
    __syncthreads();

    const int wsel = t >> 6;
    const int cp   = t & 63;        // col pair index
    const int j0   = cp * 2;

    float acc[16][2];
    #pragma unroll
    for (int r = 0; r < 16; ++r) { acc[r][0] = 0.f; acc[r][1] = 0.f; }

    for (int k = 0; k < D; k += 4) {
        float2 w[4];
        #pragma unroll
        for (int kk = 0; kk < 4; ++kk)
            w[kk] = reinterpret_cast<const float2*>(Wm + (size_t)(k + kk) * D + j0)[0];
        #pragma unroll
        for (int r = 0; r < 16; ++r) {
            float4 a = reinterpret_cast<const float4*>(&tile[wsel * 16 + r][k])[0];
            acc[r][0] += a.x * w[0].x + a.y * w[1].x + a.z * w[2].x + a.w * w[3].x;
            acc[r][1] += a.x * w[0].y + a.y * w[1].y + a.z * w[2].y + a.w * w[3].y;
        }
    }

    #pragma unroll
    for (int r = 0; r < 16; ++r) {
        int gr = r0 + wsel * 16 + r;
        if (gr < N) hw[(size_t)gr * 64 + cp] = pack_bf16(acc[r][0], acc[r][1]);
    }
}

// ---------------------------------------------------------------------------
// Pull aggregation over bf16 hW rows, fused finish:
//   out[n] = (sum_{e in csr[n]} hW[src_e]) / outdeg[n] + b
// One wave per node; lane l owns col pair {2l, 2l+1} (one uint per row).
// ---------------------------------------------------------------------------
__global__ __launch_bounds__(256) void aggregate_bf16(const unsigned int* __restrict__ hw,
                                                      const int* __restrict__ off,
                                                      const int* __restrict__ csr,
                                                      const int* __restrict__ outdeg,
                                                      const float* __restrict__ bias,
                                                      float* __restrict__ out, int N) {
    const int wid  = (int)((blockIdx.x * blockDim.x + threadIdx.x) >> 6);
    const int lane = threadIdx.x & 63;
    const int nw   = (int)((gridDim.x * blockDim.x) >> 6);
    for (int n = wid; n < N; n += nw) {
        const int e0 = off[n], e1 = off[n + 1];
        float ax = 0.f, ay = 0.f;
        int e = e0;
        for (; e + 4 <= e1; e += 4) {
            int s0 = csr[e], s1 = csr[e + 1], s2 = csr[e + 2], s3 = csr[e + 3];
            unsigned int u0 = hw[(size_t)s0 * 64 + lane];
            unsigned int u1 = hw[(size_t)s1 * 64 + lane];
            unsigned int u2 = hw[(size_t)s2 * 64 + lane];
            unsigned int u3 = hw[(size_t)s3 * 64 + lane];
            ax += __uint_as_float(u0 << 16) + __uint_as_float(u1 << 16)
                + __uint_as_float(u2 << 16) + __uint_as_float(u3 << 16);
            ay += __uint_as_float(u0 & 0xffff0000u) + __uint_as_float(u1 & 0xffff0000u)
                + __uint_as_float(u2 & 0xffff0000u) + __uint_as_float(u3 & 0xffff0000u);
        }
        for (; e < e1; ++e) {
            unsigned int u = hw[(size_t)csr[e] * 64 + lane];
            ax += __uint_as_float(u << 16);
            ay += __uint_as_float(u & 0xffff0000u);
        }
        float sc = 1.0f / (float)outdeg[n];
        float2 bb = reinterpret_cast<const float2*>(bias)[lane];
        float2 o;
        o.x = ax * sc + bb.x;
        o.y = ay * sc + bb.y;
        reinterpret_cast<float2*>(out + (size_t)n * D)[lane] = o;
    }
}

// ---------------------------------------------------------------------------
// Tier-2 (round-3) kernels: fp32 gather + separate finishing GEMM
// ---------------------------------------------------------------------------
__global__ __launch_bounds__(256) void aggregate_kernel(const float* __restrict__ h,
                                                        const int* __restrict__ off,
                                                        const int* __restrict__ csr_src,
                                                        float* __restrict__ agg, int N) {
    const int wid  = (int)((blockIdx.x * blockDim.x + threadIdx.x) >> 6);
    const int lane = threadIdx.x & 63;
    const int nw   = (int)((gridDim.x * blockDim.x) >> 6);
    for (int n = wid; n < N; n += nw) {
        const int e0 = off[n], e1 = off[n + 1];
        float2 acc = make_float2(0.f, 0.f);
        int e = e0;
        for (; e + 1 < e1; e += 2) {
            int s0 = csr_src[e], s1 = csr_src[e + 1];
            float2 a = reinterpret_cast<const float2*>(h + (size_t)s0 * D)[lane];
            float2 b = reinterpret_cast<const float2*>(h + (size_t)s1 * D)[lane];
            acc.x += a.x + b.x;
            acc.y += a.y + b.y;
        }
        if (e < e1) {
            float2 a = reinterpret_cast<const float2*>(h + (size_t)csr_src[e] * D)[lane];
            acc.x += a.x;
            acc.y += a.y;
        }
        reinterpret_cast<float2*>(agg + (size_t)n * D)[lane] = acc;
    }
}

__global__ void scatter_kernel(const float* __restrict__ h,
                               const int* __restrict__ src,
                               const int* __restrict__ dst,
                               float* __restrict__ agg, int E) {
    int wave   = (int)((blockIdx.x * blockDim.x + threadIdx.x) >> 6);
    int lane   = threadIdx.x & 63;
    int nwaves = (int)((gridDim.x * blockDim.x) >> 6);
    for (int e = wave; e < E; e += nwaves) {
        int s = src[e];
        int d = dst[e];
        const float2 v = reinterpret_cast<const float2*>(h + (size_t)s * D)[lane];
        float* arow = agg + (size_t)d * D + lane * 2;
        atomicAdd(arow + 0, v.x);
        atomicAdd(arow + 1, v.y);
    }
}

__global__ __launch_bounds__(256) void gemm_finish(float* __restrict__ out,
                                                   const float* __restrict__ Wm,
                                                   const float* __restrict__ bias,
                                                   const int* __restrict__ deg,
                                                   int N) {
    __shared__ __align__(16) float tile[64][D];
    const int r0 = blockIdx.x * 64;
    const int t  = threadIdx.x;

    #pragma unroll
    for (int i = 0; i < 8; ++i) {
        int flat4 = i * 256 + t;
        int r     = flat4 >> 5;
        int c4    = flat4 & 31;
        int gr    = r0 + r;
        float4 v  = make_float4(0.f, 0.f, 0.f, 0.f);
        if (gr < N) v = reinterpret_cast<const float4*>(out + (size_t)gr * D)[c4];
        reinterpret_cast<float4*>(&tile[r][c4 * 4])[0] = v;
    }
    __syncthreads();

    const int wsel = t >> 6;
    const int j0   = (t & 63) * 2;

    float acc[16][2];
    #pragma unroll
    for (int r = 0; r < 16; ++r) { acc[r][0] = 0.f; acc[r][1] = 0.f; }

    for (int k = 0; k < D; k += 4) {
        float2 w[4];
        #pragma unroll
        for (int kk = 0; kk < 4; ++kk)
            w[kk] = reinterpret_cast<const float2*>(Wm + (size_t)(k + kk) * D + j0)[0];
        #pragma unroll
        for (int r = 0; r < 16; ++r) {
            float4 a = reinterpret_cast<const float4*>(&tile[wsel * 16 + r][k])[0];
            acc[r][0] += a.x * w[0].x + a.y * w[1].x + a.z * w[2].x + a.w * w[3].x;
            acc[r][1] += a.x * w[0].y + a.y * w[1].y + a.z * w[2].y + a.w * w[3].y;
        }
    }

    const float2 bb = reinterpret_cast<const float2*>(bias + j0)[0];
    #pragma unroll
    for (int r = 0; r < 16; ++r) {
        int gr = r0 + wsel * 16 + r;
        if (gr < N) {
            float sc = 1.0f / (float)deg[gr];
            float2 o;
            o.x = acc[r][0] * sc + bb.x;
            o.y = acc[r][1] * sc + bb.y;
            reinterpret_cast<float2*>(out + (size_t)gr * D + j0)[0] = o;
        }
    }
}

// ---------------------------------------------------------------------------
extern "C" void kernel_launch(void* const* d_in, const int* in_sizes, int n_in,
                              void* d_out, int out_size, void* d_ws, size_t ws_size,
                              hipStream_t stream) {
    const float* h   = (const float*)d_in[0];
    const float* Wm  = (const float*)d_in[1];
    const float* bia = (const float*)d_in[2];
    const int*   src = (const int*)d_in[3];
    const int*   dst = (const int*)d_in[4];
    float*       out = (float*)d_out;

    const int N = in_sizes[0] / D;   // 100000
    const int E = in_sizes[3];       // 1700000

    const int nb     = (N + 255) >> 8;
    const int nchunk = (E + CHUNK - 1) / CHUNK;

    // common sort-pipeline footprint (ints):
    // outdeg[N] | off[N+1] | cnt[nchunk*nb] | loff[nchunk*nb] | bb[nb+1] |
    // pairs[nchunk*CHUNK] | csr[E] | [tier1 only:] hw[N*64]
    size_t base_ints  = (size_t)N + (N + 1) + (size_t)2 * nchunk * nb + (nb + 1)
                      + (size_t)nchunk * CHUNK + (size_t)E;
    size_t tier1_ints = base_ints + (size_t)N * 64;

    bool shape_ok = (N < (1 << 24)) && nb <= NB_MAX && nchunk <= NCHUNK_MAX;

    if (shape_ok && ws_size >= tier1_ints * sizeof(int)) {
        // ---- tier 1: bf16 hW gather, fused finish ----
        int* outdeg = (int*)d_ws;
        int* off    = outdeg + N;
        int* cnt_g  = off + (N + 1);
        int* loff_g = cnt_g + (size_t)nchunk * nb;
        int* bb     = loff_g + (size_t)nchunk * nb;
        unsigned int* pairs = (unsigned int*)(bb + (nb + 1));
        int* csr    = (int*)(pairs + (size_t)nchunk * CHUNK);
        unsigned int* hw = (unsigned int*)(csr + E);

        hipMemsetAsync(outdeg, 0, (size_t)N * sizeof(int), stream);

        part_chunk<<<nchunk, 256, 0, stream>>>(src, dst, pairs, cnt_g, loff_g, outdeg, E, nb);
        bucket_scan<<<1, 256, 0, stream>>>(cnt_g, bb, nb, nchunk, E);
        csr_build<<<nb, 256, 0, stream>>>(pairs, cnt_g, loff_g, bb, off, csr,
                                          nb, nchunk, N, E);

        gemm_hw<<<(N + 63) / 64, 256, 0, stream>>>(h, Wm, hw, N);

        aggregate_bf16<<<(N + 3) / 4, 256, 0, stream>>>(hw, off, csr, outdeg, bia, out, N);
    } else if (shape_ok && ws_size >= base_ints * sizeof(int)) {
        // ---- tier 2 (round-3 path): fp32 gather + finishing GEMM ----
        int* outdeg = (int*)d_ws;
        int* off    = outdeg + N;
        int* cnt_g  = off + (N + 1);
        int* loff_g = cnt_g + (size_t)nchunk * nb;
        int* bb     = loff_g + (size_t)nchunk * nb;
        unsigned int* pairs = (unsigned int*)(bb + (nb + 1));
        int* csr    = (int*)(pairs + (size_t)nchunk * CHUNK);

        hipMemsetAsync(outdeg, 0, (size_t)N * sizeof(int), stream);

        part_chunk<<<nchunk, 256, 0, stream>>>(src, dst, pairs, cnt_g, loff_g, outdeg, E, nb);
        bucket_scan<<<1, 256, 0, stream>>>(cnt_g, bb, nb, nchunk, E);
        csr_build<<<nb, 256, 0, stream>>>(pairs, cnt_g, loff_g, bb, off, csr,
                                          nb, nchunk, N, E);

        aggregate_kernel<<<(N + 3) / 4, 256, 0, stream>>>(h, off, csr, out, N);
        gemm_finish<<<(N + 63) / 64, 256, 0, stream>>>(out, Wm, bia, outdeg, N);
    } else {
        // ---- tier 3: atomic scatter fallback ----
        int* deg = (int*)d_ws;
        hipMemsetAsync(out, 0, (size_t)out_size * sizeof(float), stream);
        hipMemsetAsync(deg, 0, (size_t)N * sizeof(int), stream);
        deg_kernel<<<2048, 256, 0, stream>>>(src, deg, E);
        scatter_kernel<<<8192, 256, 0, stream>>>(h, src, dst, out, E);
        gemm_finish<<<(N + 63) / 64, 256, 0, stream>>>(out, Wm, bia, deg, N);
    }
}

// Round 5
// 278.134 us; speedup vs baseline: 5.5282x; 1.3649x over previous
//
#include <hip/hip_runtime.h>

#define D 128           // feature dim
#define CHUNK 8192      // edges per partition block
#define NCHUNK_MAX 256  // supports E <= 2M
#define NB_MAX 512      // supports N <= 131072 (bucket = 256 nodes)
#define STAGE_CAP 12288 // C2 LDS stage entries

// ---------------------------------------------------------------------------
// bf16 helpers (manual RNE pack; element 2c in low 16 bits)
// ---------------------------------------------------------------------------
__device__ __forceinline__ unsigned int pack_bf16(float a, float b) {
    unsigned int ua = __float_as_uint(a), ub = __float_as_uint(b);
    ua = (ua + 0x7fffu + ((ua >> 16) & 1u)) >> 16;
    ub = (ub + 0x7fffu + ((ub >> 16) & 1u)) >> 16;
    return (ub << 16) | (ua & 0xffffu);
}

// ---------------------------------------------------------------------------
// out-degree histogram (standalone, fallback path only)
// ---------------------------------------------------------------------------
__global__ void deg_kernel(const int* __restrict__ src, int* __restrict__ deg, int E) {
    int i = blockIdx.x * blockDim.x + threadIdx.x;
    int stride = gridDim.x * blockDim.x;
    for (; i < E; i += stride) atomicAdd(&deg[src[i]], 1);
}

// ---------------------------------------------------------------------------
// C1: partition each 8192-edge chunk by bucket (dst>>8), dense output.
// pairs word = (dst&255)<<24 | src   (requires src < 2^24)
// Also accumulates: global out-degree histogram + global bucket totals.
// ---------------------------------------------------------------------------
__global__ __launch_bounds__(256) void part_chunk(const int* __restrict__ src,
                                                  const int* __restrict__ dst,
                                                  unsigned int* __restrict__ pairs,
                                                  int* __restrict__ cnt_g,
                                                  int* __restrict__ loff_g,
                                                  int* __restrict__ outdeg,
                                                  int* __restrict__ tot,
                                                  int E, int nb) {
    __shared__ int hist[NB_MAX];
    __shared__ int lofs[NB_MAX];
    __shared__ int cur[NB_MAX];
    __shared__ unsigned int stage[CHUNK];

    const int t  = threadIdx.x;
    const int c  = blockIdx.x;
    const int e0 = c * CHUNK;
    const int n  = min(CHUNK, E - e0);

    for (int i = t; i < nb; i += 256) hist[i] = 0;
    __syncthreads();

    // pass 1: bucket histogram
    for (int i = t; i < n; i += 256) {
        int d = dst[e0 + i];
        atomicAdd(&hist[d >> 8], 1);
    }
    __syncthreads();

    if (t == 0) {
        int acc = 0;
        for (int i = 0; i < nb; ++i) { lofs[i] = acc; acc += hist[i]; }
    }
    __syncthreads();

    // export tables + bucket totals + init cursors
    for (int i = t; i < nb; i += 256) {
        int hv = hist[i];
        cnt_g[c * nb + i]  = hv;
        loff_g[c * nb + i] = lofs[i];
        if (hv) atomicAdd(&tot[i], hv);
        cur[i] = lofs[i];
    }
    __syncthreads();

    // pass 2: scatter into LDS stage + out-degree histogram
    for (int i = t; i < n; i += 256) {
        int d = dst[e0 + i];
        int s = src[e0 + i];
        atomicAdd(&outdeg[s], 1);
        int slot = atomicAdd(&cur[d >> 8], 1);
        stage[slot] = ((unsigned int)(d & 255) << 24) | (unsigned int)s;
    }
    __syncthreads();

    // pass 3: dense streamout
    for (int i = t; i < n; i += 256) pairs[e0 + i] = stage[i];
}

// ---------------------------------------------------------------------------
// C1b: tiny exclusive scan of tot[nb] -> bb[nb+1]  (one block, LDS scan)
// ---------------------------------------------------------------------------
__global__ __launch_bounds__(512) void bucket_scan(const int* __restrict__ tot,
                                                   int* __restrict__ bb, int nb) {
    __shared__ int lds[NB_MAX];
    const int t = threadIdx.x;
    int v = (t < nb) ? tot[t] : 0;
    lds[t] = v;
    __syncthreads();
    #pragma unroll
    for (int d = 1; d < NB_MAX; d <<= 1) {
        int x = (t >= d) ? lds[t - d] : 0;
        __syncthreads();
        lds[t] += x;
        __syncthreads();
    }
    if (t < nb) bb[t] = lds[t] - v;          // exclusive
    if (t == nb - 1) bb[nb] = lds[t];        // total == E
}

// ---------------------------------------------------------------------------
// C2: per-bucket counting sort by local dst -> CSR segment + off[] entries.
// ---------------------------------------------------------------------------
__global__ __launch_bounds__(256) void csr_build(const unsigned int* __restrict__ pairs,
                                                 const int* __restrict__ cnt_g,
                                                 const int* __restrict__ loff_g,
                                                 const int* __restrict__ bb,
                                                 int* __restrict__ off,
                                                 int* __restrict__ csr,
                                                 int nb, int nchunk, int N, int E) {
    __shared__ int sec_base[NCHUNK_MAX + 1];
    __shared__ int sec_lo[NCHUNK_MAX];
    __shared__ int dhist[256];
    __shared__ int dcur[256];
    __shared__ unsigned int stage[STAGE_CAP];

    const int t = threadIdx.x;
    const int b = blockIdx.x;

    for (int c = t; c < nchunk; c += 256) {
        sec_base[c] = cnt_g[c * nb + b];
        sec_lo[c]   = loff_g[c * nb + b];
    }
    if (t < 256) dhist[t] = 0;
    __syncthreads();
    if (t == 0) {
        int acc = 0;
        for (int c = 0; c < nchunk; ++c) { int v = sec_base[c]; sec_base[c] = acc; acc += v; }
        sec_base[nchunk] = acc;
    }
    __syncthreads();

    const int total  = sec_base[nchunk];
    const int base_g = bb[b];

    for (int j = t; j < total; j += 256) {
        int lo = 0, hi = nchunk - 1;
        while (lo < hi) { int mid = (lo + hi + 1) >> 1; if (sec_base[mid] <= j) lo = mid; else hi = mid - 1; }
        unsigned int p = pairs[lo * CHUNK + sec_lo[lo] + (j - sec_base[lo])];
        atomicAdd(&dhist[p >> 24], 1);
    }
    __syncthreads();

    if (t == 0) {
        int acc = 0;
        for (int i = 0; i < 256; ++i) { int v = dhist[i]; dhist[i] = acc; acc += v; }
    }
    __syncthreads();

    {
        int node = (b << 8) + t;
        if (node < N) off[node] = base_g + dhist[t];
        if (b == gridDim.x - 1 && t == 0) off[N] = E;
    }
    dcur[t] = dhist[t];
    __syncthreads();

    for (int j = t; j < total; j += 256) {
        int lo = 0, hi = nchunk - 1;
        while (lo < hi) { int mid = (lo + hi + 1) >> 1; if (sec_base[mid] <= j) lo = mid; else hi = mid - 1; }
        unsigned int p = pairs[lo * CHUNK + sec_lo[lo] + (j - sec_base[lo])];
        int slot = atomicAdd(&dcur[p >> 24], 1);
        unsigned int s = p & 0xFFFFFFu;
        if (slot < STAGE_CAP) stage[slot] = s;
        else csr[base_g + slot] = (int)s;
    }
    __syncthreads();

    int lim = min(total, STAGE_CAP);
    for (int j = t; j < lim; j += 256) csr[base_g + j] = (int)stage[j];
}

// ---------------------------------------------------------------------------
// GEMM: hw(bf16) = h @ W.
// ---------------------------------------------------------------------------
__global__ __launch_bounds__(256) void gemm_hw(const float* __restrict__ h,
                                               const float* __restrict__ Wm,
                                               unsigned int* __restrict__ hw,
                                               int N) {
    __shared__ __align__(16) float tile[64][D];
    const int r0 = blockIdx.x * 64;
    const int t  = threadIdx.x;

    #pragma unroll
    for (int i = 0; i < 8; ++i) {
        int flat4 = i * 256 + t;
        int r     = flat4 >> 5;
        int c4    = flat4 & 31;
        int gr    = r0 + r;
        float4 v  = make_float4(0.f, 0.f, 0.f, 0.f);
        if (gr < N) v = reinterpret_cast<const float4*>(h + (size_t)gr * D)[c4];
        reinterpret_cast<float4*>(&tile[r][c4 * 4])[0] = v;
    }
    __syncthreads();

    const int wsel = t >> 6;
    const int cp   = t & 63;
    const int j0   = cp * 2;

    float acc[16][2];
    #pragma unroll
    for (int r = 0; r < 16; ++r) { acc[r][0] = 0.f; acc[r][1] = 0.f; }

    for (int k = 0; k < D; k += 4) {
        float2 w[4];
        #pragma unroll
        for (int kk = 0; kk < 4; ++kk)
            w[kk] = reinterpret_cast<const float2*>(Wm + (size_t)(k + kk) * D + j0)[0];
        #pragma unroll
        for (int r = 0; r < 16; ++r) {
            float4 a = reinterpret_cast<const float4*>(&tile[wsel * 16 + r][k])[0];
            acc[r][0] += a.x * w[0].x + a.y * w[1].x + a.z * w[2].x + a.w * w[3].x;
            acc[r][1] += a.x * w[0].y + a.y * w[1].y + a.z * w[2].y + a.w * w[3].y;
        }
    }

    #pragma unroll
    for (int r = 0; r < 16; ++r) {
        int gr = r0 + wsel * 16 + r;
        if (gr < N) hw[(size_t)gr * 64 + cp] = pack_bf16(acc[r][0], acc[r][1]);
    }
}

// ---------------------------------------------------------------------------
// Pull aggregation over bf16 hW rows, fused finish:
//   out[n] = (sum_{e in csr[n]} hW[src_e]) / outdeg[n] + b
// ---------------------------------------------------------------------------
__global__ __launch_bounds__(256) void aggregate_bf16(const unsigned int* __restrict__ hw,
                                                      const int* __restrict__ off,
                                                      const int* __restrict__ csr,
                                                      const int* __restrict__ outdeg,
                                                      const float* __restrict__ bias,
                                                      float* __restrict__ out, int N) {
    const int wid  = (int)((blockIdx.x * blockDim.x + threadIdx.x) >> 6);
    const int lane = threadIdx.x & 63;
    const int nw   = (int)((gridDim.x * blockDim.x) >> 6);
    for (int n = wid; n < N; n += nw) {
        const int e0 = off[n], e1 = off[n + 1];
        float ax = 0.f, ay = 0.f;
        int e = e0;
        for (; e + 4 <= e1; e += 4) {
            int s0 = csr[e], s1 = csr[e + 1], s2 = csr[e + 2], s3 = csr[e + 3];
            unsigned int u0 = hw[(size_t)s0 * 64 + lane];
            unsigned int u1 = hw[(size_t)s1 * 64 + lane];
            unsigned int u2 = hw[(size_t)s2 * 64 + lane];
            unsigned int u3 = hw[(size_t)s3 * 64 + lane];
            ax += __uint_as_float(u0 << 16) + __uint_as_float(u1 << 16)
                + __uint_as_float(u2 << 16) + __uint_as_float(u3 << 16);
            ay += __uint_as_float(u0 & 0xffff0000u) + __uint_as_float(u1 & 0xffff0000u)
                + __uint_as_float(u2 & 0xffff0000u) + __uint_as_float(u3 & 0xffff0000u);
        }
        for (; e < e1; ++e) {
            unsigned int u = hw[(size_t)csr[e] * 64 + lane];
            ax += __uint_as_float(u << 16);
            ay += __uint_as_float(u & 0xffff0000u);
        }
        float sc = 1.0f / (float)outdeg[n];
        float2 bb = reinterpret_cast<const float2*>(bias)[lane];
        float2 o;
        o.x = ax * sc + bb.x;
        o.y = ay * sc + bb.y;
        reinterpret_cast<float2*>(out + (size_t)n * D)[lane] = o;
    }
}

// ---------------------------------------------------------------------------
// Tier-2 kernels: fp32 gather + separate finishing GEMM
// ---------------------------------------------------------------------------
__global__ __launch_bounds__(256) void aggregate_kernel(const float* __restrict__ h,
                                                        const int* __restrict__ off,
                                                        const int* __restrict__ csr_src,
                                                        float* __restrict__ agg, int N) {
    const int wid  = (int)((blockIdx.x * blockDim.x + threadIdx.x) >> 6);
    const int lane = threadIdx.x & 63;
    const int nw   = (int)((gridDim.x * blockDim.x) >> 6);
    for (int n = wid; n < N; n += nw) {
        const int e0 = off[n], e1 = off[n + 1];
        float2 acc = make_float2(0.f, 0.f);
        int e = e0;
        for (; e + 1 < e1; e += 2) {
            int s0 = csr_src[e], s1 = csr_src[e + 1];
            float2 a = reinterpret_cast<const float2*>(h + (size_t)s0 * D)[lane];
            float2 b = reinterpret_cast<const float2*>(h + (size_t)s1 * D)[lane];
            acc.x += a.x + b.x;
            acc.y += a.y + b.y;
        }
        if (e < e1) {
            float2 a = reinterpret_cast<const float2*>(h + (size_t)csr_src[e] * D)[lane];
            acc.x += a.x;
            acc.y += a.y;
        }
        reinterpret_cast<float2*>(agg + (size_t)n * D)[lane] = acc;
    }
}

__global__ void scatter_kernel(const float* __restrict__ h,
                               const int* __restrict__ src,
                               const int* __restrict__ dst,
                               float* __restrict__ agg, int E) {
    int wave   = (int)((blockIdx.x * blockDim.x + threadIdx.x) >> 6);
    int lane   = threadIdx.x & 63;
    int nwaves = (int)((gridDim.x * blockDim.x) >> 6);
    for (int e = wave; e < E; e += nwaves) {
        int s = src[e];
        int d = dst[e];
        const float2 v = reinterpret_cast<const float2*>(h + (size_t)s * D)[lane];
        float* arow = agg + (size_t)d * D + lane * 2;
        atomicAdd(arow + 0, v.x);
        atomicAdd(arow + 1, v.y);
    }
}

__global__ __launch_bounds__(256) void gemm_finish(float* __restrict__ out,
                                                   const float* __restrict__ Wm,
                                                   const float* __restrict__ bias,
                                                   const int* __restrict__ deg,
                                                   int N) {
    __shared__ __align__(16) float tile[64][D];
    const int r0 = blockIdx.x * 64;
    const int t  = threadIdx.x;

    #pragma unroll
    for (int i = 0; i < 8; ++i) {
        int flat4 = i * 256 + t;
        int r     = flat4 >> 5;
        int c4    = flat4 & 31;
        int gr    = r0 + r;
        float4 v  = make_float4(0.f, 0.f, 0.f, 0.f);
        if (gr < N) v = reinterpret_cast<const float4*>(out + (size_t)gr * D)[c4];
        reinterpret_cast<float4*>(&tile[r][c4 * 4])[0] = v;
    }
    __syncthreads();

    const int wsel = t >> 6;
    const int j0   = (t & 63) * 2;

    float acc[16][2];
    #pragma unroll
    for (int r = 0; r < 16; ++r) { acc[r][0] = 0.f; acc[r][1] = 0.f; }

    for (int k = 0; k < D; k += 4) {
        float2 w[4];
        #pragma unroll
        for (int kk = 0; kk < 4; ++kk)
            w[kk] = reinterpret_cast<const float2*>(Wm + (size_t)(k + kk) * D + j0)[0];
        #pragma unroll
        for (int r = 0; r < 16; ++r) {
            float4 a = reinterpret_cast<const float4*>(&tile[wsel * 16 + r][k])[0];
            acc[r][0] += a.x * w[0].x + a.y * w[1].x + a.z * w[2].x + a.w * w[3].x;
            acc[r][1] += a.x * w[0].y + a.y * w[1].y + a.z * w[2].y + a.w * w[3].y;
        }
    }

    const float2 bb = reinterpret_cast<const float2*>(bias + j0)[0];
    #pragma unroll
    for (int r = 0; r < 16; ++r) {
        int gr = r0 + wsel * 16 + r;
        if (gr < N) {
            float sc = 1.0f / (float)deg[gr];
            float2 o;
            o.x = acc[r][0] * sc + bb.x;
            o.y = acc[r][1] * sc + bb.y;
            reinterpret_cast<float2*>(out + (size_t)gr * D + j0)[0] = o;
        }
    }
}

// ---------------------------------------------------------------------------
extern "C" void kernel_launch(void* const* d_in, const int* in_sizes, int n_in,
                              void* d_out, int out_size, void* d_ws, size_t ws_size,
                              hipStream_t stream) {
    const float* h   = (const float*)d_in[0];
    const float* Wm  = (const float*)d_in[1];
    const float* bia = (const float*)d_in[2];
    const int*   src = (const int*)d_in[3];
    const int*   dst = (const int*)d_in[4];
    float*       out = (float*)d_out;

    const int N = in_sizes[0] / D;   // 100000
    const int E = in_sizes[3];       // 1700000

    const int nb     = (N + 255) >> 8;
    const int nchunk = (E + CHUNK - 1) / CHUNK;

    // ws (ints): outdeg[N] | tot[NB_MAX] | off[N+1] | cnt[nchunk*nb] |
    //            loff[nchunk*nb] | bb[nb+1] | pairs[nchunk*CHUNK] | csr[E] |
    //            [tier1:] hw[N*64]
    size_t base_ints  = (size_t)N + NB_MAX + (N + 1) + (size_t)2 * nchunk * nb
                      + (nb + 1) + (size_t)nchunk * CHUNK + (size_t)E;
    size_t tier1_ints = base_ints + (size_t)N * 64;

    bool shape_ok = (N < (1 << 24)) && nb <= NB_MAX && nchunk <= NCHUNK_MAX;

    if (shape_ok && ws_size >= tier1_ints * sizeof(int)) {
        // ---- tier 1: bf16 hW gather, fused finish ----
        int* outdeg = (int*)d_ws;
        int* tot    = outdeg + N;
        int* off    = tot + NB_MAX;
        int* cnt_g  = off + (N + 1);
        int* loff_g = cnt_g + (size_t)nchunk * nb;
        int* bb     = loff_g + (size_t)nchunk * nb;
        unsigned int* pairs = (unsigned int*)(bb + (nb + 1));
        int* csr    = (int*)(pairs + (size_t)nchunk * CHUNK);
        unsigned int* hw = (unsigned int*)(csr + E);

        hipMemsetAsync(outdeg, 0, ((size_t)N + NB_MAX) * sizeof(int), stream);

        part_chunk<<<nchunk, 256, 0, stream>>>(src, dst, pairs, cnt_g, loff_g,
                                               outdeg, tot, E, nb);
        bucket_scan<<<1, NB_MAX, 0, stream>>>(tot, bb, nb);
        csr_build<<<nb, 256, 0, stream>>>(pairs, cnt_g, loff_g, bb, off, csr,
                                          nb, nchunk, N, E);

        gemm_hw<<<(N + 63) / 64, 256, 0, stream>>>(h, Wm, hw, N);

        aggregate_bf16<<<(N + 3) / 4, 256, 0, stream>>>(hw, off, csr, outdeg, bia, out, N);
    } else if (shape_ok && ws_size >= base_ints * sizeof(int)) {
        // ---- tier 2: fp32 gather + finishing GEMM ----
        int* outdeg = (int*)d_ws;
        int* tot    = outdeg + N;
        int* off    = tot + NB_MAX;
        int* cnt_g  = off + (N + 1);
        int* loff_g = cnt_g + (size_t)nchunk * nb;
        int* bb     = loff_g + (size_t)nchunk * nb;
        unsigned int* pairs = (unsigned int*)(bb + (nb + 1));
        int* csr    = (int*)(pairs + (size_t)nchunk * CHUNK);

        hipMemsetAsync(outdeg, 0, ((size_t)N + NB_MAX) * sizeof(int), stream);

        part_chunk<<<nchunk, 256, 0, stream>>>(src, dst, pairs, cnt_g, loff_g,
                                               outdeg, tot, E, nb);
        bucket_scan<<<1, NB_MAX, 0, stream>>>(tot, bb, nb);
        csr_build<<<nb, 256, 0, stream>>>(pairs, cnt_g, loff_g, bb, off, csr,
                                          nb, nchunk, N, E);

        aggregate_kernel<<<(N + 3) / 4, 256, 0, stream>>>(h, off, csr, out, N);
        gemm_finish<<<(N + 63) / 64, 256, 0, stream>>>(out, Wm, bia, outdeg, N);
    } else {
        // ---- tier 3: atomic scatter fallback ----
        int* deg = (int*)d_ws;
        hipMemsetAsync(out, 0, (size_t)out_size * sizeof(float), stream);
        hipMemsetAsync(deg, 0, (size_t)N * sizeof(int), stream);
        deg_kernel<<<2048, 256, 0, stream>>>(src, deg, E);
        scatter_kernel<<<8192, 256, 0, stream>>>(h, src, dst, out, E);
        gemm_finish<<<(N + 63) / 64, 256, 0, stream>>>(out, Wm, bia, deg, N);
    }
}